// Round 6
// baseline (246.206 us; speedup 1.0000x reference)
//
#include <hip/hip_runtime.h>
#include <hip/hip_bf16.h>

typedef __attribute__((ext_vector_type(4))) float f32x4;
typedef __attribute__((ext_vector_type(8))) short bf16x8;

#define MFMA(a, b, c) __builtin_amdgcn_mfma_f32_16x16x32_bf16(a, b, c, 0, 0, 0)

__device__ __forceinline__ short f2bf(float f) {
    union { float f; unsigned u; } v; v.f = f;
    unsigned r = v.u + 0x7fffu + ((v.u >> 16) & 1u);
    return (short)(r >> 16);
}

__device__ __forceinline__ short f2bf_h(float f) {
    __hip_bfloat16 h = __float2bfloat16(f);
    return *reinterpret_cast<const short*>(&h);
}

__device__ __forceinline__ bf16x8 cvt8h(f32x4 a, f32x4 b) {
    bf16x8 r;
    #pragma unroll
    for (int i = 0; i < 4; ++i) {
        r[i]     = f2bf_h(a[i]);
        r[4 + i] = f2bf_h(b[i]);
    }
    return r;
}

__device__ __forceinline__ void gll16(const void* g, const void* l) {
    __builtin_amdgcn_global_load_lds(
        (const __attribute__((address_space(1))) void*)g,
        (__attribute__((address_space(3))) void*)l, 16, 0, 0);
}

// ws layout:
//   W_all [320][1024] bf16 @ short 0      (rows: seg*64+col; segs q,k1,v1,k2,v2)
//   weff  [1024][64]  bf16 @ short 327680
//   b_all [320]       f32  @ byte 786432
#define WS_WEFF   327680
#define WS_BALL_B 786432

__global__ __launch_bounds__(256) void prep_kernel(
        const float* __restrict__ lq_w, const float* __restrict__ lk1_w,
        const float* __restrict__ lk2_w, const float* __restrict__ lv1_w,
        const float* __restrict__ lv2_w, const float* __restrict__ lh_w,
        const float* __restrict__ lq_b, const float* __restrict__ lk1_b,
        const float* __restrict__ lk2_b, const float* __restrict__ lv1_b,
        const float* __restrict__ lv2_b,
        short* __restrict__ W_all, short* __restrict__ weff,
        float* __restrict__ b_all) {
    int t = blockIdx.x * 256 + threadIdx.x;
    if (t < 327680) {                       // W_all
        int row = t >> 10, col = t & 1023;
        int seg = row >> 6, sr = row & 63;
        const float* src = (seg == 0) ? lq_w : (seg == 1) ? lk1_w
                         : (seg == 2) ? lv1_w : (seg == 3) ? lk2_w : lv2_w;
        W_all[t] = f2bf(src[sr * 1024 + col]);
    } else if (t < 393216) {                // weff
        int i = t - 327680;
        int j = i >> 6, d = i & 63;
        float s = 0.f;
        #pragma unroll
        for (int h = 0; h < 16; ++h) s += lh_w[j * 1024 + h * 64 + d];
        weff[i] = f2bf(s);
    } else if (t < 393536) {                // b_all
        int i = t - 393216;
        int seg = i >> 6, si = i & 63;
        const float* src = (seg == 0) ? lq_b : (seg == 1) ? lk1_b
                         : (seg == 2) ? lv1_b : (seg == 3) ? lk2_b : lv2_b;
        b_all[i] = src[si];
    }
}

// Fused: block = 16 rows, 4 waves, K=1024 in 8 bodies of BK=128 (4 substeps
// of k=32). A (Q/K/V f32): 512B-contiguous-per-row gll into 2-deep LDS ring
// (24KB/slot) — big DRAM bursts. W: inline-asm dwordx4 into 2 rotating reg
// banks (W[g+2] issued at substep g). Counted vmcnt per substep: 11,11,5,5
// (s2's wait also drains next body's A). Raw s_barrier once per body.
__global__ __launch_bounds__(256, 3) void fused_kernel(
        const float* __restrict__ Q, const float* __restrict__ K,
        const float* __restrict__ V, const short* __restrict__ W_all,
        const float* __restrict__ b_all, const short* __restrict__ weff,
        const float* __restrict__ lh_b, float* __restrict__ out) {
    __shared__ __align__(16) char lds[49152];   // 2 x 24KB A ring; epi reuse
    const int tid  = threadIdx.x;
    const int wid  = tid >> 6;
    const int lane = tid & 63;
    const int lrow = lane & 15;
    const int lkg  = lane >> 4;
    const int RB   = blockIdx.x * 16;

    // A staging: 24 gll per body (1KB each = 2 rows x 512B), 6 per wave.
    // i = wid*6+u -> input i>>3, rowpair i&7. Source XOR-swizzled (cell^row&7),
    // LDS dest linear [input][row][512B].
    const float* asrc[6];
    int adst[6];
    #pragma unroll
    for (int u = 0; u < 6; ++u) {
        const int i   = wid * 6 + u;
        const int inp = i >> 3;
        const int rp  = i & 7;
        const int row = rp * 2 + (lane >> 5);
        const int gc  = (lane & 31) ^ (row & 7);
        const float* base = (inp == 0) ? Q : (inp == 1) ? K : V;
        asrc[u] = base + (size_t)(RB + row) * 1024 + gc * 4;
        adst[u] = inp * 8192 + rp * 1024;
    }

    // W fragment pointers (L2): row = seg*64 + wid*16 + lrow
    const short* wsrc[5];
    #pragma unroll
    for (int j = 0; j < 5; ++j)
        wsrc[j] = W_all + (size_t)(j * 64 + wid * 16 + lrow) * 1024 + lkg * 8;

    f32x4 acc[5];
    #pragma unroll
    for (int j = 0; j < 5; ++j) acc[j] = (f32x4){0.f, 0.f, 0.f, 0.f};

    bf16x8 wA[5], wB[5];
    const int r7 = lrow & 7;

    // ---- prologue: A(0)x6, W[0]x5, W[1]x5; wait A(0); barrier ----
    #pragma unroll
    for (int u = 0; u < 6; ++u) gll16(asrc[u], lds + adst[u]);
    #pragma unroll
    for (int j = 0; j < 5; ++j)
        asm volatile("global_load_dwordx4 %0, %1, off"
                     : "=&v"(wA[j]) : "v"(wsrc[j]) : "memory");
    #pragma unroll
    for (int j = 0; j < 5; ++j)
        asm volatile("global_load_dwordx4 %0, %1, off"
                     : "=&v"(wB[j]) : "v"(wsrc[j] + 32) : "memory");
    asm volatile("s_waitcnt vmcnt(10)" ::: "memory");
    __builtin_amdgcn_sched_barrier(0);
    __builtin_amdgcn_s_barrier();
    __builtin_amdgcn_sched_barrier(0);

#define SUBSTEP(S, BANK, WAIT)                                                 \
    {                                                                          \
        asm volatile("s_waitcnt " WAIT ::: "memory");                          \
        __builtin_amdgcn_sched_barrier(0);                                     \
        const int c0 = (((S) * 8 + lkg * 2)     ^ r7) << 4;                    \
        const int c1 = (((S) * 8 + lkg * 2 + 1) ^ r7) << 4;                    \
        const char* Ar = Acur + lrow * 512;                                    \
        f32x4 q0 = *(const f32x4*)(Ar + c0);                                   \
        f32x4 q1 = *(const f32x4*)(Ar + c1);                                   \
        f32x4 k0 = *(const f32x4*)(Ar + 8192 + c0);                            \
        f32x4 k1 = *(const f32x4*)(Ar + 8192 + c1);                            \
        f32x4 v0 = *(const f32x4*)(Ar + 16384 + c0);                           \
        f32x4 v1 = *(const f32x4*)(Ar + 16384 + c1);                           \
        const bf16x8 aq = cvt8h(q0, q1);                                       \
        const bf16x8 ak = cvt8h(k0, k1);                                       \
        const bf16x8 av = cvt8h(v0, v1);                                       \
        acc[0] = MFMA(aq, BANK[0], acc[0]);                                    \
        acc[1] = MFMA(ak, BANK[1], acc[1]);                                    \
        acc[2] = MFMA(ak, BANK[2], acc[2]);                                    \
        acc[3] = MFMA(av, BANK[3], acc[3]);                                    \
        acc[4] = MFMA(av, BANK[4], acc[4]);                                    \
        int gg = 4 * C + (S) + 2;                                              \
        if (gg > 31) gg = 31;                                                  \
        _Pragma("unroll")                                                      \
        for (int j = 0; j < 5; ++j)                                            \
            asm volatile("global_load_dwordx4 %0, %1, off"                     \
                         : "=&v"(BANK[j]) : "v"(wsrc[j] + gg * 32) : "memory");\
    }

    #pragma unroll 1
    for (int C = 0; C < 8; ++C) {
        const char* Acur = lds + (C & 1) * 24576;
        char* Anx = lds + ((C + 1) & 1) * 24576;
        const int kn = ((C < 7) ? (C + 1) : 7) * 128;   // float offset (512B)
        #pragma unroll
        for (int u = 0; u < 6; ++u) gll16(asrc[u] + kn, Anx + adst[u]);

        SUBSTEP(0, wA, "vmcnt(11)")
        SUBSTEP(1, wB, "vmcnt(11)")
        SUBSTEP(2, wA, "vmcnt(5)")     // also drains A(C+1)
        SUBSTEP(3, wB, "vmcnt(5)")

        __builtin_amdgcn_sched_barrier(0);
        __builtin_amdgcn_s_barrier();
        __builtin_amdgcn_sched_barrier(0);
    }
#undef SUBSTEP

    // drain tail junk (lands in slot0, which epi overwrites after the barrier)
    asm volatile("s_waitcnt vmcnt(0)" ::: "memory");
    __builtin_amdgcn_sched_barrier(0);
    __syncthreads();

    // ---- gate epilogue: acc+bias -> epi f32 [16][324] ----
    float* epi = (float*)lds;
    #pragma unroll
    for (int j = 0; j < 5; ++j) {
        const int colj = j * 64 + wid * 16 + lrow;
        const float bb = b_all[colj];
        #pragma unroll
        for (int i = 0; i < 4; ++i)
            epi[(lkg * 4 + i) * 324 + colj] = acc[j][i] + bb;
    }
    __syncthreads();

    // gate: row r = lrow; partial over lkg (16 q-dims each); reduce xor 16,32
    const int r = lrow;
    const float* er = epi + r * 324;
    float p1 = 0.f, p2 = 0.f;
    #pragma unroll
    for (int jj = 0; jj < 16; ++jj) {
        const float qv = er[lkg * 16 + jj];
        p1 += qv * er[64  + lkg * 16 + jj];    // q . k1
        p2 += qv * er[192 + lkg * 16 + jj];    // q . k2
    }
    p1 += __shfl_xor(p1, 16, 64); p1 += __shfl_xor(p1, 32, 64);
    p2 += __shfl_xor(p2, 16, 64); p2 += __shfl_xor(p2, 32, 64);
    const float mx = fmaxf(p1, p2);
    const float e1 = __expf(p1 - mx);
    const float e2 = __expf(p2 - mx);
    const float inv = 1.f / (e1 + e2);
    const float g1 = e1 * inv, g2 = e2 * inv;

    short* head_s = (short*)(lds + 21504);  // [16][72] bf16 (above epi's 20.7KB)
    const int cb = wid * 16 + lkg * 4;
    #pragma unroll
    for (int j2 = 0; j2 < 4; ++j2) {
        const float h = g1 * er[128 + cb + j2] + g2 * er[256 + cb + j2];
        head_s[r * 72 + cb + j2] = f2bf_h(h);
    }
    __syncthreads();

    // ---- phase 2: out[16 x 1024] = head @ W_eff^T + lh_b; wave = 256 cols ----
    const bf16x8 ha0 = *(const bf16x8*)(head_s + lrow * 72 + lkg * 8);
    const bf16x8 ha1 = *(const bf16x8*)(head_s + lrow * 72 + 32 + lkg * 8);
    const int cgbase = wid * 256;
    #pragma unroll 4
    for (int jt = 0; jt < 16; ++jt) {
        const int col = cgbase + jt * 16 + lrow;
        const float bb = lh_b[col];
        f32x4 a = {bb, bb, bb, bb};
        const short* wp = weff + col * 64 + lkg * 8;
        a = MFMA(ha0, *(const bf16x8*)(wp), a);
        a = MFMA(ha1, *(const bf16x8*)(wp + 32), a);
        #pragma unroll
        for (int i = 0; i < 4; ++i)
            out[(size_t)(RB + lkg * 4 + i) * 1024 + col] = a[i];
    }
}

extern "C" void kernel_launch(void* const* d_in, const int* in_sizes, int n_in,
                              void* d_out, int out_size, void* d_ws, size_t ws_size,
                              hipStream_t stream) {
    const float* Q     = (const float*)d_in[0];
    const float* K     = (const float*)d_in[1];
    const float* V     = (const float*)d_in[2];
    const float* lq_w  = (const float*)d_in[3];
    const float* lq_b  = (const float*)d_in[4];
    const float* lk1_w = (const float*)d_in[5];
    const float* lk1_b = (const float*)d_in[6];
    const float* lk2_w = (const float*)d_in[7];
    const float* lk2_b = (const float*)d_in[8];
    const float* lv1_w = (const float*)d_in[9];
    const float* lv1_b = (const float*)d_in[10];
    const float* lv2_w = (const float*)d_in[11];
    const float* lv2_b = (const float*)d_in[12];
    const float* lh_w  = (const float*)d_in[13];
    const float* lh_b  = (const float*)d_in[14];
    float* out = (float*)d_out;

    short* W_all = (short*)d_ws;
    short* weff  = W_all + WS_WEFF;
    float* b_all = (float*)((char*)d_ws + WS_BALL_B);

    prep_kernel<<<1538, 256, 0, stream>>>(lq_w, lk1_w, lk2_w, lv1_w, lv2_w, lh_w,
                                          lq_b, lk1_b, lk2_b, lv1_b, lv2_b,
                                          W_all, weff, b_all);
    fused_kernel<<<2048, 256, 0, stream>>>(Q, K, V, W_all, b_all, weff, lh_b, out);
}